// Round 6
// baseline (194.070 us; speedup 1.0000x reference)
//
#include <hip/hip_runtime.h>

// MultiScaleRoIAlign round 6: chunk-looped, double-buffered LDS pipeline with
// global_load_lds staging (T3 minimal 2-phase template).
// B=2, C=256, L=256 -> K=512 ROIs. out (K,256,7,7) fp32.
// Levels: (200,200,1/4) (100,100,1/8) (50,50,1/16) (25,25,1/32). SR=2, bilinear, avg 4.
//
// roi_setup: per-ROI params + tap tables -> d_ws (dense-stride offsets,
//   edge cases folded as weight=0; garbage reads are finite via zero-guard).
// msroi_pipe: block = (roi, 64 channels), 512 thr, loops 8 chunks of CC=8.
//   stage(n+1) via global_load_lds (lane-contiguous dense LDS dest, per-lane
//   global src) overlaps compute(n); one vmcnt-drain + barrier per chunk.

#define NCH 256
#define CC 8
#define CHUNKS 8
#define CPB (CC * CHUNKS)   // 64 channels per block
#define PM 1153             // LDS floats per channel plane (odd: bank decorrelation)
#define WSTRIDE 80
#define NROI 512
#define THREADS 512
#define NPIX (CC * 49)      // 392 compute threads

typedef const __attribute__((address_space(1))) void* gas_ptr;
typedef __attribute__((address_space(3))) void* las_ptr;

// ws per-ROI layout (words):
//  0 lvl, 1 px0, 2 py0, 3 pw_cnt, 4 pdense, 5 W, 6 HW, 7 nit
//  16..29 xle[14] (xlo-px0; edge: last col, lx=0)
//  30..43 lx[14] bits
//  44..57 r0e[14] ((ylo-py0)*pw_cnt dense stride; edge: last row, ly=0)
//  58..71 ly[14] bits

__device__ __forceinline__ void roi_scalars(const float* __restrict__ boxes, int k,
    int& lvl, int& H, int& W, float& x1, float& y1, float& bin_w, float& bin_h,
    int& px0, int& py0, int& pw_cnt, int& ph_cnt)
{
    float bx1 = boxes[k*4+0], by1 = boxes[k*4+1], bx2 = boxes[k*4+2], by2 = boxes[k*4+3];
    float area = (bx2-bx1)*(by2-by1);
    float s = sqrtf(area);
    float lvlf = floorf(4.0f + log2f(s*(1.0f/224.0f)) + 1e-6f);
    lvlf = fminf(fmaxf(lvlf, 2.0f), 5.0f);
    lvl = (int)lvlf - 2;
    float scale;
    if (lvl == 0)      { H=200; W=200; scale=0.25f;    }
    else if (lvl == 1) { H=100; W=100; scale=0.125f;   }
    else if (lvl == 2) { H=50;  W=50;  scale=0.0625f;  }
    else               { H=25;  W=25;  scale=0.03125f; }
    x1 = bx1*scale; y1 = by1*scale;
    float roi_w = fmaxf(bx2*scale - x1, 1.0f);
    float roi_h = fmaxf(by2*scale - y1, 1.0f);
    bin_w = roi_w*(1.0f/7.0f); bin_h = roi_h*(1.0f/7.0f);
    float c; int lo;
    c = fmaxf(x1 + 0.25f*bin_w, 0.0f); lo = (int)c; px0 = (lo >= W-1) ? (W-1) : lo;
    c = fmaxf(x1 + 6.75f*bin_w, 0.0f); lo = (int)c; int px1e = (lo >= W-1) ? (W-1) : (lo+1);
    c = fmaxf(y1 + 0.25f*bin_h, 0.0f); lo = (int)c; py0 = (lo >= H-1) ? (H-1) : lo;
    c = fmaxf(y1 + 6.75f*bin_h, 0.0f); lo = (int)c; int py1e = (lo >= H-1) ? (H-1) : (lo+1);
    pw_cnt = px1e - px0 + 1;
    ph_cnt = py1e - py0 + 1;
}

__global__ __launch_bounds__(64) void roi_setup(const float* __restrict__ boxes,
                                                int* __restrict__ ws)
{
    int k = blockIdx.x*64 + threadIdx.x;
    if (k >= NROI) return;
    int lvl, H, W, px0, py0, pw_cnt, ph_cnt;
    float x1, y1, bin_w, bin_h;
    roi_scalars(boxes, k, lvl, H, W, x1, y1, bin_w, bin_h, px0, py0, pw_cnt, ph_cnt);
    int pdense = pw_cnt * ph_cnt;
    int* p = ws + k*WSTRIDE;
    p[0]=lvl; p[1]=px0; p[2]=py0; p[3]=pw_cnt; p[4]=pdense; p[5]=W; p[6]=H*W;
    p[7]=(pdense + THREADS - 1)/THREADS;
    for (int i = 0; i < 14; ++i) {
        float c = fmaxf(x1 + ((float)i*0.5f + 0.25f)*bin_w, 0.0f);
        int lo = (int)c; int xle; float lx;
        if (lo >= W-1) { xle = (W-1) - px0; lx = 0.0f; }   // +1 read weight-0
        else           { xle = lo - px0;    lx = c - (float)lo; }
        p[16+i] = xle;
        p[30+i] = __float_as_int(lx);
    }
    for (int i = 0; i < 14; ++i) {
        float c = fmaxf(y1 + ((float)i*0.5f + 0.25f)*bin_h, 0.0f);
        int lo = (int)c; int r; float ly;
        if (lo >= H-1) { r = (H-1) - py0; ly = 0.0f; }     // +row read weight-0
        else           { r = lo - py0;    ly = c - (float)lo; }
        p[44+i] = r*pw_cnt;
        p[58+i] = __float_as_int(ly);
    }
}

template<bool USE_WS>
__global__ __launch_bounds__(THREADS) void msroi_pipe(
    const float* __restrict__ f0, const float* __restrict__ f1,
    const float* __restrict__ f2, const float* __restrict__ f3,
    const float* __restrict__ boxes, const int* __restrict__ ws,
    float* __restrict__ out)
{
    __shared__ float s_patch[2][CC * PM];   // 73,792 B -> 2 blocks/CU

    const int tid = threadIdx.x;
    const int k  = blockIdx.y;
    const int c0 = blockIdx.x * CPB;

    int lvl, px0, py0, pw_cnt, pdense, W, HW, nit;
    int Hf = 0; float x1f = 0, y1f = 0, bwf = 0, bhf = 0;
    if constexpr (USE_WS) {
        const int* p = ws + k*WSTRIDE;       // uniform -> scalar loads
        lvl = p[0]; px0 = p[1]; py0 = p[2]; pw_cnt = p[3];
        pdense = p[4]; W = p[5]; HW = p[6]; nit = p[7];
    } else {
        int ph_cnt;
        roi_scalars(boxes, k, lvl, Hf, W, x1f, y1f, bwf, bhf, px0, py0, pw_cnt, ph_cnt);
        pdense = pw_cnt * ph_cnt; HW = Hf * W;
        nit = (pdense + THREADS - 1)/THREADS;
    }

    const float* feat = (lvl == 0) ? f0 : (lvl == 1) ? f1 : (lvl == 2) ? f2 : f3;
    const int b = k >> 8;
    const float* bp = feat + (size_t)(b*NCH + c0) * (size_t)HW;

    // ---- per-output taps in registers (chunk-invariant) ----
    int aR0C0 = 0, aR0C1 = 0, aR1C0 = 0, aR1C1 = 0, clbase = 0;
    float lx0 = 0, lx1 = 0, ly0 = 0, ly1 = 0, hx0 = 0, hx1 = 0, hy0 = 0, hy1 = 0;
    if (tid < NPIX) {
        int cl = tid / 49, pix = tid - cl*49;
        int ph = pix / 7,  pw  = pix - ph*7;
        clbase = cl * PM;
        int xe0, xe1, r00, r01;
        if constexpr (USE_WS) {
            const int* p = ws + k*WSTRIDE;
            xe0 = p[16 + 2*pw]; xe1 = p[17 + 2*pw];
            lx0 = __int_as_float(p[30 + 2*pw]); lx1 = __int_as_float(p[31 + 2*pw]);
            r00 = p[44 + 2*ph]; r01 = p[45 + 2*ph];
            ly0 = __int_as_float(p[58 + 2*ph]); ly1 = __int_as_float(p[59 + 2*ph]);
        } else {
            auto tapx = [&](int i, int& xe, float& lx) {
                float c = fmaxf(x1f + ((float)i*0.5f + 0.25f)*bwf, 0.0f);
                int lo = (int)c;
                if (lo >= W-1) { xe = (W-1) - px0; lx = 0.0f; }
                else           { xe = lo - px0;    lx = c - (float)lo; }
            };
            auto tapy = [&](int i, int& r0, float& ly) {
                float c = fmaxf(y1f + ((float)i*0.5f + 0.25f)*bhf, 0.0f);
                int lo = (int)c;
                if (lo >= Hf-1) { r0 = ((Hf-1) - py0)*pw_cnt; ly = 0.0f; }
                else            { r0 = (lo - py0)*pw_cnt;     ly = c - (float)lo; }
            };
            tapx(2*pw, xe0, lx0); tapx(2*pw+1, xe1, lx1);
            tapy(2*ph, r00, ly0); tapy(2*ph+1, r01, ly1);
        }
        aR0C0 = r00 + xe0; aR0C1 = r00 + xe1;
        aR1C0 = r01 + xe0; aR1C1 = r01 + xe1;
        hx0 = 1.0f - lx0; hx1 = 1.0f - lx1;
        hy0 = 1.0f - ly0; hy1 = 1.0f - ly1;
    }

    // ---- zero-guard strip [pdense, pdense+123): keeps weight-0 reads finite ----
    {
        int glen = PM - pdense; if (glen > 123) glen = 123;
        int tot = 2 * CC * glen;
        for (int z = tid; z < tot; z += THREADS) {
            int bufc = z / glen, off = z - bufc*glen;
            s_patch[bufc >> 3][(bufc & 7)*PM + pdense + off] = 0.0f;
        }
    }

    const float inv_pw = 1.0f / (float)pw_cnt;
    const int pstr = pw_cnt;

    auto stage = [&](int chunk, int buf) {
        const float* cbp = bp + (size_t)(chunk * CC) * (size_t)HW;
        for (int it = 0; it < nit; ++it) {
            int i = it*THREADS + tid;
            int gi = (i < pdense) ? i : (pdense - 1);
            int r = (int)((float)gi * inv_pw);
            int col = gi - r*pw_cnt;
            if (col < 0)             { col += pw_cnt; --r; }
            else if (col >= pw_cnt)  { col -= pw_cnt; ++r; }
            int go = (py0 + r)*W + (px0 + col);
            const float* src = cbp + go;
            float* dst = &s_patch[buf][i];   // lane-contiguous dense dest
#pragma unroll
            for (int j = 0; j < CC; ++j) {
                __builtin_amdgcn_global_load_lds((gas_ptr)(src + (size_t)j*HW),
                                                 (las_ptr)(dst + j*PM), 4, 0, 0);
            }
        }
    };

    __syncthreads();                 // zeros visible before DMA
    int cur = 0;
    stage(0, 0);
    asm volatile("s_waitcnt vmcnt(0)" ::: "memory");
    __syncthreads();

    const size_t obase = ((size_t)k*NCH + c0)*49 + tid;
    for (int n = 0; n < CHUNKS; ++n) {
        if (n + 1 < CHUNKS) stage(n + 1, cur ^ 1);   // prefetch overlaps compute
        if (tid < NPIX) {
            const float* patch = &s_patch[cur][clbase];
            float acc;
            {   int a = aR0C0;
                float v00 = patch[a], v01 = patch[a+1];
                float v10 = patch[a+pstr], v11 = patch[a+pstr+1];
                acc  = hy0*(hx0*v00 + lx0*v01) + ly0*(hx0*v10 + lx0*v11); }
            {   int a = aR0C1;
                float v00 = patch[a], v01 = patch[a+1];
                float v10 = patch[a+pstr], v11 = patch[a+pstr+1];
                acc += hy0*(hx1*v00 + lx1*v01) + ly0*(hx1*v10 + lx1*v11); }
            {   int a = aR1C0;
                float v00 = patch[a], v01 = patch[a+1];
                float v10 = patch[a+pstr], v11 = patch[a+pstr+1];
                acc += hy1*(hx0*v00 + lx0*v01) + ly1*(hx0*v10 + lx0*v11); }
            {   int a = aR1C1;
                float v00 = patch[a], v01 = patch[a+1];
                float v10 = patch[a+pstr], v11 = patch[a+pstr+1];
                acc += hy1*(hx1*v00 + lx1*v01) + ly1*(hx1*v10 + lx1*v11); }
            out[obase + (size_t)n * NPIX] = acc * 0.25f;
        }
        asm volatile("s_waitcnt vmcnt(0)" ::: "memory");
        __syncthreads();
        cur ^= 1;
    }
}

extern "C" void kernel_launch(void* const* d_in, const int* in_sizes, int n_in,
                              void* d_out, int out_size, void* d_ws, size_t ws_size,
                              hipStream_t stream)
{
    const float* f0 = (const float*)d_in[0];
    const float* f1 = (const float*)d_in[1];
    const float* f2 = (const float*)d_in[2];
    const float* f3 = (const float*)d_in[3];
    const float* boxes = (const float*)d_in[4];
    float* out = (float*)d_out;

    dim3 grid(NCH / CPB, NROI, 1);   // (4, 512)
    dim3 block(THREADS, 1, 1);
    size_t need = (size_t)NROI * WSTRIDE * sizeof(int);

    if (d_ws != nullptr && ws_size >= need) {
        roi_setup<<<dim3((NROI + 63)/64), dim3(64), 0, stream>>>(boxes, (int*)d_ws);
        msroi_pipe<true><<<grid, block, 0, stream>>>(f0, f1, f2, f3, boxes,
                                                     (const int*)d_ws, out);
    } else {
        msroi_pipe<false><<<grid, block, 0, stream>>>(f0, f1, f2, f3, boxes,
                                                      nullptr, out);
    }
}